// Round 2
// baseline (2885.215 us; speedup 1.0000x reference)
//
#include <hip/hip_runtime.h>
#include <math.h>

#define NSPEC 8192
#define NRXN  16384
#define NBAL  7680
#define NUNBAL 512

// workspace byte offsets (all 16B-aligned)
#define OFF_LOGC 0u          // float[8192]   : log(conc) per species
#define OFF_LOGV 32768u      // float[16384]  : log_v, then v after k_exp
#define OFF_ACC  98304u      // float[8192]   : S @ v accumulator (full species)
#define OFF_CNT  131072u     // unsigned[1]   : COO entry counter
#define OFF_ENT  131088u     // unsigned[cap] : packed COO entries

// pack: s(13b) << 17 | r(14b) << 3 | (val+2)(3b)

__global__ void k_init(const float* __restrict__ cb, const int* __restrict__ bidx,
                       const int* __restrict__ uidx, const float* __restrict__ lcu,
                       const float* __restrict__ lkcat,
                       float* __restrict__ logc, float* __restrict__ logv,
                       float* __restrict__ acc, unsigned* __restrict__ cnt) {
    int i = blockIdx.x * blockDim.x + threadIdx.x;
    if (i == 0) *cnt = 0u;
    if (i < NRXN)  logv[i] = lkcat[i];
    if (i < NSPEC) acc[i] = 0.0f;
    if (i < NBAL)  logc[bidx[i]] = logf(cb[i]);
    if (i < NUNBAL) logc[uidx[i]] = lcu[i];   // log(exp(x)) == x
}

__global__ __launch_bounds__(256) void k_scan(const float* __restrict__ S,
                                              const float* __restrict__ logc,
                                              float* __restrict__ logv,
                                              unsigned* __restrict__ cnt,
                                              unsigned* __restrict__ entries,
                                              unsigned cap) {
    const int lane = threadIdx.x & 63;
    const long long nvec = (long long)NSPEC * (long long)NRXN / 4;
    const long long stride = (long long)gridDim.x * blockDim.x;
    for (long long i = (long long)blockIdx.x * blockDim.x + threadIdx.x;
         i < nvec; i += stride) {
        const float4 f = ((const float4*)S)[i];
        const float vals[4] = {f.x, f.y, f.z, f.w};
        #pragma unroll
        for (int j = 0; j < 4; ++j) {
            float val = vals[j];
            bool nz = (val != 0.0f);
            unsigned long long m = __ballot(nz);
            if (m != 0ULL) {                       // wave-uniform
                int s = (int)(i >> 12);            // i / 4096 vec4s per row
                int r = (((int)i & 4095) << 2) + j;
                int leader = __ffsll((unsigned long long)m) - 1;
                unsigned base = 0;
                if (lane == leader)
                    base = atomicAdd(cnt, (unsigned)__popcll(m));
                base = (unsigned)__shfl((int)base, leader, 64);
                if (nz) {
                    int iv = (int)val;             // exact: S is integer-valued
                    if (val < 0.0f)
                        atomicAdd(&logv[r], (float)(-iv) * logc[s]);
                    unsigned pos = base +
                        (unsigned)__popcll(m & ((1ULL << lane) - 1ULL));
                    if (pos < cap)
                        entries[pos] = ((unsigned)s << 17) |
                                       ((unsigned)r << 3) |
                                       (unsigned)(iv + 2);
                }
            }
        }
    }
}

__global__ void k_exp(float* __restrict__ logv) {
    int i = blockIdx.x * blockDim.x + threadIdx.x;
    if (i < NRXN) logv[i] = expf(logv[i]);
}

__global__ void k_scatter(const unsigned* __restrict__ entries,
                          const unsigned* __restrict__ cnt,
                          const float* __restrict__ v,
                          float* __restrict__ acc, unsigned cap) {
    unsigned n = *cnt;
    if (n > cap) n = cap;
    unsigned stride = gridDim.x * blockDim.x;
    for (unsigned i = blockIdx.x * blockDim.x + threadIdx.x; i < n; i += stride) {
        unsigned e = entries[i];
        int s = (int)(e >> 17);
        int r = (int)((e >> 3) & 0x3FFFu);
        float iv = (float)((int)(e & 7u) - 2);
        atomicAdd(&acc[s], iv * v[r]);
    }
}

// fallback second full pass over S when ws can't hold the COO list
__global__ __launch_bounds__(256) void k_pass2(const float* __restrict__ S,
                                               const float* __restrict__ v,
                                               float* __restrict__ acc) {
    const long long nvec = (long long)NSPEC * (long long)NRXN / 4;
    const long long stride = (long long)gridDim.x * blockDim.x;
    for (long long i = (long long)blockIdx.x * blockDim.x + threadIdx.x;
         i < nvec; i += stride) {
        const float4 f = ((const float4*)S)[i];
        const float vals[4] = {f.x, f.y, f.z, f.w};
        if (f.x != 0.0f || f.y != 0.0f || f.z != 0.0f || f.w != 0.0f) {
            int s = (int)(i >> 12);
            int rbase = (((int)i & 4095) << 2);
            #pragma unroll
            for (int j = 0; j < 4; ++j) {
                float val = vals[j];
                if (val != 0.0f)
                    atomicAdd(&acc[s], val * v[rbase + j]);
            }
        }
    }
}

__global__ void k_gather(const float* __restrict__ acc,
                         const int* __restrict__ bidx,
                         float* __restrict__ out) {
    int i = blockIdx.x * blockDim.x + threadIdx.x;
    if (i < NBAL) out[i] = acc[bidx[i]];
}

extern "C" void kernel_launch(void* const* d_in, const int* in_sizes, int n_in,
                              void* d_out, int out_size, void* d_ws, size_t ws_size,
                              hipStream_t stream) {
    const float* cb    = (const float*)d_in[0];
    const float* S     = (const float*)d_in[1];
    const int*   bidx  = (const int*)d_in[2];
    const int*   uidx  = (const int*)d_in[3];
    const float* lcu   = (const float*)d_in[4];
    const float* lkcat = (const float*)d_in[5];
    float* out = (float*)d_out;

    char* ws = (char*)d_ws;
    float*    logc    = (float*)(ws + OFF_LOGC);
    float*    logv    = (float*)(ws + OFF_LOGV);   // becomes v after k_exp
    float*    acc     = (float*)(ws + OFF_ACC);
    unsigned* cnt     = (unsigned*)(ws + OFF_CNT);
    unsigned* entries = (unsigned*)(ws + OFF_ENT);

    unsigned cap = 0;
    if (ws_size > OFF_ENT + 16)
        cap = (unsigned)((ws_size - OFF_ENT) / 4);

    k_init<<<(NRXN + 255) / 256, 256, 0, stream>>>(cb, bidx, uidx, lcu, lkcat,
                                                   logc, logv, acc, cnt);
    if (cap >= 400000u) {
        // single-pass-over-S COO path (~215k expected nonzeros)
        k_scan<<<2048, 256, 0, stream>>>(S, logc, logv, cnt, entries, cap);
        k_exp<<<(NRXN + 255) / 256, 256, 0, stream>>>(logv);
        k_scatter<<<512, 256, 0, stream>>>(entries, cnt, logv, acc, cap);
    } else {
        // fallback: two full passes over S
        k_scan<<<2048, 256, 0, stream>>>(S, logc, logv, cnt, entries, 0u);
        k_exp<<<(NRXN + 255) / 256, 256, 0, stream>>>(logv);
        k_pass2<<<2048, 256, 0, stream>>>(S, logv, acc);
    }
    k_gather<<<(NBAL + 255) / 256, 256, 0, stream>>>(acc, bidx, out);
}

// Round 3
// 712.870 us; speedup vs baseline: 4.0473x; 4.0473x over previous
//
#include <hip/hip_runtime.h>
#include <math.h>

#define NSPEC 8192
#define NRXN  16384
#define NBAL  7680
#define NUNBAL 512

#define NBLOCK 2048
#define NTHREAD 256
#define NWAVE ((NBLOCK * NTHREAD) / 64)   // 8192 waves
#define SLOTS 64                          // per-wave private COO slots (mean ~26)

// workspace byte offsets (all 16B-aligned)
#define OFF_LOGC  0u                                  // float[8192]
#define OFF_LOGV  32768u                              // float[16384] -> v after k_exp
#define OFF_ACC   98304u                              // float[8192]
#define OFF_CNT   131072u                             // unsigned[1] spill counter
#define OFF_WCNT  131088u                             // unsigned[NWAVE]
#define OFF_SLICE (OFF_WCNT + NWAVE * 4u)             // 163856: unsigned[NWAVE*SLOTS]
#define OFF_SPILL (OFF_SLICE + NWAVE * SLOTS * 4u)    // 2261008: unsigned[spillcap]

// pack: s(13b) << 17 | r(14b) << 3 | (val+2)(3b)

__global__ void k_init(const float* __restrict__ cb, const int* __restrict__ bidx,
                       const int* __restrict__ uidx, const float* __restrict__ lcu,
                       const float* __restrict__ lkcat,
                       float* __restrict__ logc, float* __restrict__ logv,
                       float* __restrict__ acc, unsigned* __restrict__ cnt) {
    int i = blockIdx.x * blockDim.x + threadIdx.x;
    if (i == 0) *cnt = 0u;
    if (i < NRXN)  logv[i] = lkcat[i];
    if (i < NSPEC) acc[i] = 0.0f;
    if (i < NBAL)  logc[bidx[i]] = logf(cb[i]);
    if (i < NUNBAL) logc[uidx[i]] = lcu[i];   // log(exp(x)) == x
}

// single pass over S: logv atomics (non-returning) + per-wave private COO append
// (NO shared counter, NO shfl in the hot path)
__global__ __launch_bounds__(256) void k_scan(const float* __restrict__ S,
                                              const float* __restrict__ logc,
                                              float* __restrict__ logv,
                                              unsigned* __restrict__ wcnt,
                                              unsigned* __restrict__ slices,
                                              unsigned* __restrict__ spillcnt,
                                              unsigned* __restrict__ spill,
                                              unsigned spillcap) {
    const int lane = threadIdx.x & 63;
    const unsigned gid = blockIdx.x * blockDim.x + threadIdx.x;
    const unsigned wave = gid >> 6;
    unsigned* const slice = slices + (size_t)wave * SLOTS;
    unsigned base = 0;                                 // wave-uniform register
    const long long nvec = (long long)NSPEC * (long long)NRXN / 4;
    const long long stride = (long long)gridDim.x * blockDim.x;
    for (long long i = gid; i < nvec; i += stride) {
        const float4 f = ((const float4*)S)[i];
        bool any = (f.x != 0.0f) | (f.y != 0.0f) | (f.z != 0.0f) | (f.w != 0.0f);
        if (__ballot(any) == 0ULL) continue;           // ~66% of wave-groups skip
        const float vals[4] = {f.x, f.y, f.z, f.w};
        const int s = (int)(i >> 12);                  // 4096 vec4s per row
        const int rbase = ((int)i & 4095) << 2;
        #pragma unroll
        for (int j = 0; j < 4; ++j) {
            float val = vals[j];
            bool nz = (val != 0.0f);
            unsigned long long m = __ballot(nz);
            if (m == 0ULL) continue;
            if (nz) {
                int r = rbase + j;
                int iv = (int)val;                     // exact: S integer-valued
                if (val < 0.0f)
                    atomicAdd(&logv[r], (float)(-iv) * logc[s]);
                unsigned pos = base +
                    (unsigned)__popcll(m & ((1ULL << lane) - 1ULL));
                unsigned e = ((unsigned)s << 17) | ((unsigned)r << 3) |
                             (unsigned)(iv + 2);
                if (pos < SLOTS) {
                    slice[pos] = e;
                } else {                               // astronomically rare
                    unsigned sp = atomicAdd(spillcnt, 1u);
                    if (sp < spillcap) spill[sp] = e;
                }
            }
            base += (unsigned)__popcll(m);
        }
    }
    if (lane == 0) wcnt[wave] = (base < SLOTS) ? base : SLOTS;
}

__global__ void k_exp(float* __restrict__ logv) {
    int i = blockIdx.x * blockDim.x + threadIdx.x;
    if (i < NRXN) logv[i] = expf(logv[i]);
}

__global__ __launch_bounds__(256) void k_scatter(const unsigned* __restrict__ slices,
                                                 const unsigned* __restrict__ wcnt,
                                                 const unsigned* __restrict__ spill,
                                                 const unsigned* __restrict__ spillcnt,
                                                 unsigned spillcap,
                                                 const float* __restrict__ v,
                                                 float* __restrict__ acc) {
    unsigned idx = blockIdx.x * blockDim.x + threadIdx.x;
    if (idx < (unsigned)NWAVE * SLOTS) {               // SLOTS == 64
        unsigned wave = idx >> 6, slot = idx & 63u;
        if (slot < wcnt[wave]) {
            unsigned e = slices[idx];
            int s = (int)(e >> 17);
            int r = (int)((e >> 3) & 0x3FFFu);
            float iv = (float)((int)(e & 7u) - 2);
            atomicAdd(&acc[s], iv * v[r]);
        }
    }
    unsigned n = *spillcnt;
    if (n > spillcap) n = spillcap;
    unsigned stride = gridDim.x * blockDim.x;
    for (unsigned i = idx; i < n; i += stride) {
        unsigned e = spill[i];
        int s = (int)(e >> 17);
        int r = (int)((e >> 3) & 0x3FFFu);
        float iv = (float)((int)(e & 7u) - 2);
        atomicAdd(&acc[s], iv * v[r]);
    }
}

// ---- fallback (tiny ws): no COO, two full passes over S ----
__global__ __launch_bounds__(256) void k_scan_noent(const float* __restrict__ S,
                                                    const float* __restrict__ logc,
                                                    float* __restrict__ logv) {
    const long long nvec = (long long)NSPEC * (long long)NRXN / 4;
    const long long stride = (long long)gridDim.x * blockDim.x;
    for (long long i = (long long)blockIdx.x * blockDim.x + threadIdx.x;
         i < nvec; i += stride) {
        const float4 f = ((const float4*)S)[i];
        const float vals[4] = {f.x, f.y, f.z, f.w};
        if (f.x < 0.0f || f.y < 0.0f || f.z < 0.0f || f.w < 0.0f) {
            int s = (int)(i >> 12);
            int rbase = ((int)i & 4095) << 2;
            #pragma unroll
            for (int j = 0; j < 4; ++j)
                if (vals[j] < 0.0f)
                    atomicAdd(&logv[rbase + j], -vals[j] * logc[s]);
        }
    }
}

__global__ __launch_bounds__(256) void k_pass2(const float* __restrict__ S,
                                               const float* __restrict__ v,
                                               float* __restrict__ acc) {
    const long long nvec = (long long)NSPEC * (long long)NRXN / 4;
    const long long stride = (long long)gridDim.x * blockDim.x;
    for (long long i = (long long)blockIdx.x * blockDim.x + threadIdx.x;
         i < nvec; i += stride) {
        const float4 f = ((const float4*)S)[i];
        const float vals[4] = {f.x, f.y, f.z, f.w};
        if (f.x != 0.0f || f.y != 0.0f || f.z != 0.0f || f.w != 0.0f) {
            int s = (int)(i >> 12);
            int rbase = ((int)i & 4095) << 2;
            #pragma unroll
            for (int j = 0; j < 4; ++j)
                if (vals[j] != 0.0f)
                    atomicAdd(&acc[s], vals[j] * v[rbase + j]);
        }
    }
}

__global__ void k_gather(const float* __restrict__ acc,
                         const int* __restrict__ bidx,
                         float* __restrict__ out) {
    int i = blockIdx.x * blockDim.x + threadIdx.x;
    if (i < NBAL) out[i] = acc[bidx[i]];
}

extern "C" void kernel_launch(void* const* d_in, const int* in_sizes, int n_in,
                              void* d_out, int out_size, void* d_ws, size_t ws_size,
                              hipStream_t stream) {
    const float* cb    = (const float*)d_in[0];
    const float* S     = (const float*)d_in[1];
    const int*   bidx  = (const int*)d_in[2];
    const int*   uidx  = (const int*)d_in[3];
    const float* lcu   = (const float*)d_in[4];
    const float* lkcat = (const float*)d_in[5];
    float* out = (float*)d_out;

    char* ws = (char*)d_ws;
    float*    logc    = (float*)(ws + OFF_LOGC);
    float*    logv    = (float*)(ws + OFF_LOGV);   // becomes v after k_exp
    float*    acc     = (float*)(ws + OFF_ACC);
    unsigned* cnt     = (unsigned*)(ws + OFF_CNT);
    unsigned* wcnt    = (unsigned*)(ws + OFF_WCNT);
    unsigned* slices  = (unsigned*)(ws + OFF_SLICE);
    unsigned* spill   = (unsigned*)(ws + OFF_SPILL);

    k_init<<<(NRXN + 255) / 256, 256, 0, stream>>>(cb, bidx, uidx, lcu, lkcat,
                                                   logc, logv, acc, cnt);
    if (ws_size >= OFF_SPILL + 65536u) {
        unsigned spillcap = (unsigned)((ws_size - OFF_SPILL) / 4);
        k_scan<<<NBLOCK, NTHREAD, 0, stream>>>(S, logc, logv, wcnt, slices,
                                               cnt, spill, spillcap);
        k_exp<<<(NRXN + 255) / 256, 256, 0, stream>>>(logv);
        k_scatter<<<NBLOCK, NTHREAD, 0, stream>>>(slices, wcnt, spill, cnt,
                                                  spillcap, logv, acc);
    } else {
        k_scan_noent<<<NBLOCK, NTHREAD, 0, stream>>>(S, logc, logv);
        k_exp<<<(NRXN + 255) / 256, 256, 0, stream>>>(logv);
        k_pass2<<<NBLOCK, NTHREAD, 0, stream>>>(S, logv, acc);
    }
    k_gather<<<(NBAL + 255) / 256, 256, 0, stream>>>(acc, bidx, out);
}